// Round 2
// baseline (441.728 us; speedup 1.0000x reference)
//
#include <hip/hip_runtime.h>

// InterConv: B=2048, F=39, E=64, C=64, P = F*(F-1)/2 = 741
// out[b*(C*P) + c*P + p] = relu( x[b,ii[p]]·Wi[c] + x[b,jj[p]]·Wj[c] + bias[c] )
//
// v2 design vs v1 (resubmit after infra failure; no functional change):
//  - W no longer staged in LDS (32 KB total, L1/L2-resident; read as float4 in GEMM).
//  - x staged untransposed [f][e] -> conflict-free float4 copy; GEMM reads are
//    broadcast ds_read_b128.
//  - LDS = union(xL 2496, A 5248) + bias = 21.2 KB -> 7 blocks/CU (28 waves/CU),
//    up from 3 blocks/CU (12 waves) at 47.3 KB.
//  - pair table dropped; (i,j) computed per-thread in registers (3 pairs/thread).
//  - phase 2 inverted: p fixed per thread, c inner -> (i,j) read once, gathers
//    near-broadcast, stores stay lane-coalesced 256B/wave.

#define BATCH 2048
#define FDIM  39
#define EDIM  64
#define CDIM  64
#define NPAIR 741
#define ASTR  41    // A leading-dim pad (odd stride -> spread banks)

__global__ __launch_bounds__(256) void interconv_fused(
    const float* __restrict__ x,     // [B, F, E]
    const float* __restrict__ Wg,    // [C, 1, 2, E] flat: c*128 + which*64 + e
    const float* __restrict__ bias,  // [C]
    float* __restrict__ out)         // [B, C*P] with layout c*P + p
{
    // A[128][ASTR] aliases the x staging buffer (xL only live during GEMM).
    __shared__ float smem[128 * ASTR];   // 5248 floats = 20992 B
    __shared__ float sbias[CDIM];

    float* xL = smem;   // [FDIM][EDIM], natural row-major (no transpose)
    float* A  = smem;   // [cw][ASTR], cw = which*64 + c

    const int tid = threadIdx.x;
    const int b   = blockIdx.x;
    const float* xg = x + (size_t)b * (FDIM * EDIM);

    // ---- phase 0: stage x (624 float4, contiguous, conflict-free) ----
    for (int q = tid; q < (FDIM * EDIM) / 4; q += 256)
        ((float4*)xL)[q] = ((const float4*)xg)[q];
    if (tid < CDIM) sbias[tid] = bias[tid];

    // ---- per-thread pair indices (pure VALU, overlaps staging) ----
    // p -> (i,j), i<j, row-major triu order. S(i) = i*(77-i)/2.
    const int  p0   = tid;
    const int  p1   = tid + 256;
    const bool has2 = (tid + 512 < NPAIR);          // tid < 229
    const int  p2   = has2 ? tid + 512 : NPAIR - 1; // clamp keeps index valid
    int iv[3], jv[3];
    {
        const int pp[3] = {p0, p1, p2};
#pragma unroll
        for (int t = 0; t < 3; ++t) {
            int p = pp[t];
            int i = (int)floorf((77.0f - sqrtf(static_cast<float>(5929 - 8 * p))) * 0.5f);
            i = i < 0 ? 0 : (i > FDIM - 2 ? FDIM - 2 : i);
            while ((i + 1) * (77 - (i + 1)) / 2 <= p) ++i;  // fixup sqrt rounding
            while (i * (77 - i) / 2 > p) --i;
            iv[t] = i;
            jv[t] = p - i * (77 - i) / 2 + i + 1;
        }
    }
    const int i0 = iv[0], j0 = jv[0];
    const int i1 = iv[1], j1 = jv[1];
    const int i2 = iv[2], j2 = jv[2];

    __syncthreads();

    // ---- phase 1: GEMM, per-thread 5f x 4cw tile, K=64 ----
    // W rows read straight from global: row (cw) = Wg + (cw&63)*128 + (cw>>6)*64,
    // contiguous in e -> float4 loads, L1/L2-hit (W is 32 KB total, shared by all blocks).
    const int ft  = tid >> 5;   // 0..7  -> f0 = ft*5 covers f 0..39 (f=39 pad, discarded)
    const int ct  = tid & 31;   // 0..31 -> cw0 = ct*4
    const int f0  = ft * 5;
    const int cw0 = ct * 4;

    const float* wrp[4];
#pragma unroll
    for (int q = 0; q < 4; ++q) {
        const int cw = cw0 + q;
        wrp[q] = Wg + (cw & 63) * 128 + (cw >> 6) * 64;
    }

    float acc[5][4];
#pragma unroll
    for (int a = 0; a < 5; ++a)
#pragma unroll
        for (int q = 0; q < 4; ++q) acc[a][q] = 0.0f;

    // Same e-ascending fmaf chain as v1 -> bit-identical accumulation order.
#pragma unroll 4
    for (int e0 = 0; e0 < EDIM; e0 += 4) {
        const float4 w0 = *(const float4*)(wrp[0] + e0);
        const float4 w1 = *(const float4*)(wrp[1] + e0);
        const float4 w2 = *(const float4*)(wrp[2] + e0);
        const float4 w3 = *(const float4*)(wrp[3] + e0);
#pragma unroll
        for (int a = 0; a < 5; ++a) {
            // broadcast ds_read_b128; f=39 row reads scratch within smem (discarded)
            const float4 xv = *(const float4*)(xL + (f0 + a) * EDIM + e0);
            acc[a][0] = fmaf(xv.w, w0.w, fmaf(xv.z, w0.z, fmaf(xv.y, w0.y, fmaf(xv.x, w0.x, acc[a][0]))));
            acc[a][1] = fmaf(xv.w, w1.w, fmaf(xv.z, w1.z, fmaf(xv.y, w1.y, fmaf(xv.x, w1.x, acc[a][1]))));
            acc[a][2] = fmaf(xv.w, w2.w, fmaf(xv.z, w2.z, fmaf(xv.y, w2.y, fmaf(xv.x, w2.x, acc[a][2]))));
            acc[a][3] = fmaf(xv.w, w3.w, fmaf(xv.z, w3.z, fmaf(xv.y, w3.y, fmaf(xv.x, w3.x, acc[a][3]))));
        }
    }
    __syncthreads();  // all xL reads done before A aliases it

    // ---- phase 1.5: write A[cw][f] ----
#pragma unroll
    for (int q = 0; q < 4; ++q)
#pragma unroll
        for (int a = 0; a < 5; ++a)
            A[(cw0 + q) * ASTR + f0 + a] = acc[a][q];
    __syncthreads();

    // ---- phase 2: gather + bias + relu; p fixed per thread, c inner ----
    // Stores: lane-consecutive p -> 256B/wave coalesced. Gathers: consecutive
    // lanes share i (near-broadcast) and read consecutive j (conflict-light).
    float* outb = out + (size_t)b * (CDIM * NPAIR);
    const float* rI = A;
    const float* rJ = A + 64 * ASTR;
    float* oc = outb;
#pragma unroll 2
    for (int c = 0; c < CDIM; ++c) {
        const float bc = sbias[c];
        const float v0 = rI[i0] + rJ[j0] + bc;   // same add order as v1 (exactness)
        const float v1 = rI[i1] + rJ[j1] + bc;
        oc[p0] = v0 > 0.0f ? v0 : 0.0f;
        oc[p1] = v1 > 0.0f ? v1 : 0.0f;
        if (has2) {
            const float v2 = rI[i2] + rJ[j2] + bc;
            oc[p2] = v2 > 0.0f ? v2 : 0.0f;
        }
        rI += ASTR; rJ += ASTR; oc += NPAIR;
    }
}

extern "C" void kernel_launch(void* const* d_in, const int* in_sizes, int n_in,
                              void* d_out, int out_size, void* d_ws, size_t ws_size,
                              hipStream_t stream) {
    const float* x    = (const float*)d_in[0];
    const float* W    = (const float*)d_in[1];
    const float* bias = (const float*)d_in[2];
    float* out        = (float*)d_out;

    interconv_fused<<<dim3(BATCH), dim3(256), 0, stream>>>(x, W, bias, out);
}

// Round 4
// 440.950 us; speedup vs baseline: 1.0018x; 1.0018x over previous
//
#include <hip/hip_runtime.h>

// InterConv: B=2048, F=39, E=64, C=64, P = F*(F-1)/2 = 741
// out[b*(C*P) + c*P + p] = relu( x[b,ii[p]]·Wi[c] + x[b,jj[p]]·Wj[c] + bias[c] )
//
// v3 (resubmit after infra failure; identical logic): phase 2 uses float4 stores.
//  - 4 consecutive c-rows = 2964 dwords = 741 exact float4 chunks, 16B-aligned
//    (rows individually are misaligned: 741*4 = 2964 B = 46 lines + 20 B).
//  - thread t owns chunks {t, t+256, t+512}; per-element (i, j, dc) precomputed
//    ONCE (invariant across the 16 c-groups); loop over groups does only
//    2 LDS gathers + bias-select + relu per element + one dwordx4 store.
//  - store instrs per thread: 192 dword -> <=48 dwordx4 (4x fewer, all aligned).
//  - LDS gather pattern: per wave, j spans <39 consecutive dwords -> <=2-way
//    bank aliasing (free); i near-broadcast.

#define BATCH 2048
#define FDIM  39
#define EDIM  64
#define CDIM  64
#define NPAIR 741
#define ASTR  41    // A leading-dim pad (odd stride -> spread banks)

__global__ __launch_bounds__(256) void interconv_fused(
    const float* __restrict__ x,     // [B, F, E]
    const float* __restrict__ Wg,    // [C, 1, 2, E] flat: c*128 + which*64 + e
    const float* __restrict__ bias,  // [C]
    float* __restrict__ out)         // [B, C*P] with layout c*P + p
{
    // A[128][ASTR] aliases the x staging buffer (xL only live during GEMM).
    __shared__ float smem[128 * ASTR];   // 5248 floats = 20992 B
    __shared__ float sbias[CDIM];

    float* xL = smem;   // [FDIM][EDIM], natural row-major (no transpose)
    float* A  = smem;   // [cw][ASTR], cw = which*64 + c

    const int tid = threadIdx.x;
    const int b   = blockIdx.x;
    const float* xg = x + (size_t)b * (FDIM * EDIM);

    // ---- phase 0: stage x (624 float4, contiguous, conflict-free) ----
    for (int q = tid; q < (FDIM * EDIM) / 4; q += 256)
        ((float4*)xL)[q] = ((const float4*)xg)[q];
    if (tid < CDIM) sbias[tid] = bias[tid];

    // ---- per-thread chunk precompute (pure VALU, overlaps staging) ----
    // chunk k covers dwords 4k..4k+3 of a 4-c-row group (2964 dwords, 741 chunks).
    // element g = 4k+m: dc = g/741 (row within group), p = g - dc*741,
    // p -> (i,j): i<j, row-major triu. S(i) = i*(77-i)/2.
    int offIb[3][4];   // byte offset into rI base: (dc*ASTR + i)*4
    int offJb[3][4];   // byte offset into rJ base: (dc*ASTR + j)*4
    unsigned dcs[3];   // per chunk: 4 x 2-bit dc
#pragma unroll
    for (int t = 0; t < 3; ++t) {
        const int k = tid + t * 256;   // may be >= 741 for t==2 (store is skipped)
        unsigned dpk = 0;
#pragma unroll
        for (int m = 0; m < 4; ++m) {
            int g = 4 * k + m;
            if (g >= 4 * NPAIR) g = 4 * NPAIR - 1;   // clamp: keep math in-range
            const int dc = (g >= 3 * NPAIR) ? 3 : (g >= 2 * NPAIR) ? 2 : (g >= NPAIR) ? 1 : 0;
            const int p  = g - dc * NPAIR;
            int i = (int)floorf((77.0f - sqrtf(static_cast<float>(5929 - 8 * p))) * 0.5f);
            i = i < 0 ? 0 : (i > FDIM - 2 ? FDIM - 2 : i);
            while ((i + 1) * (77 - (i + 1)) / 2 <= p) ++i;  // fixup sqrt rounding
            while (i * (77 - i) / 2 > p) --i;
            const int j = p - i * (77 - i) / 2 + i + 1;
            offIb[t][m] = (dc * ASTR + i) << 2;
            offJb[t][m] = (dc * ASTR + j) << 2;
            dpk |= (unsigned)dc << (2 * m);
        }
        dcs[t] = dpk;
    }

    __syncthreads();

    // ---- phase 1: GEMM, per-thread 5f x 4cw tile, K=64 ----
    // W rows read straight from global: row (cw) = Wg + (cw&63)*128 + (cw>>6)*64,
    // contiguous in e -> float4 loads, L1/L2-hit (W is 32 KB total).
    const int ft  = tid >> 5;   // 0..7  -> f0 = ft*5 covers f 0..39 (f=39 pad, discarded)
    const int ct  = tid & 31;   // 0..31 -> cw0 = ct*4
    const int f0  = ft * 5;
    const int cw0 = ct * 4;

    const float* wrp[4];
#pragma unroll
    for (int q = 0; q < 4; ++q) {
        const int cw = cw0 + q;
        wrp[q] = Wg + (cw & 63) * 128 + (cw >> 6) * 64;
    }

    float acc[5][4];
#pragma unroll
    for (int a = 0; a < 5; ++a)
#pragma unroll
        for (int q = 0; q < 4; ++q) acc[a][q] = 0.0f;

    // e-ascending fmaf chain -> bit-identical accumulation order vs v1/v2.
#pragma unroll 4
    for (int e0 = 0; e0 < EDIM; e0 += 4) {
        const float4 w0 = *(const float4*)(wrp[0] + e0);
        const float4 w1 = *(const float4*)(wrp[1] + e0);
        const float4 w2 = *(const float4*)(wrp[2] + e0);
        const float4 w3 = *(const float4*)(wrp[3] + e0);
#pragma unroll
        for (int a = 0; a < 5; ++a) {
            const float4 xv = *(const float4*)(xL + (f0 + a) * EDIM + e0);
            acc[a][0] = fmaf(xv.w, w0.w, fmaf(xv.z, w0.z, fmaf(xv.y, w0.y, fmaf(xv.x, w0.x, acc[a][0]))));
            acc[a][1] = fmaf(xv.w, w1.w, fmaf(xv.z, w1.z, fmaf(xv.y, w1.y, fmaf(xv.x, w1.x, acc[a][1]))));
            acc[a][2] = fmaf(xv.w, w2.w, fmaf(xv.z, w2.z, fmaf(xv.y, w2.y, fmaf(xv.x, w2.x, acc[a][2]))));
            acc[a][3] = fmaf(xv.w, w3.w, fmaf(xv.z, w3.z, fmaf(xv.y, w3.y, fmaf(xv.x, w3.x, acc[a][3]))));
        }
    }
    __syncthreads();  // all xL reads done before A aliases it

    // ---- phase 1.5: write A[cw][f] ----
#pragma unroll
    for (int q = 0; q < 4; ++q)
#pragma unroll
        for (int a = 0; a < 5; ++a)
            A[(cw0 + q) * ASTR + f0 + a] = acc[a][q];
    __syncthreads();

    // ---- phase 2: 16 groups of 4 c-rows; float4-assemble + aligned dwordx4 store ----
    float* outb = out + (size_t)b * (CDIM * NPAIR);
    for (int g4 = 0; g4 < 16; ++g4) {
        const int c0 = g4 * 4;
        const char* rI = (const char*)(A + c0 * ASTR);          // dc=0 I-row base
        const char* rJ = (const char*)(A + (64 + c0) * ASTR);   // dc=0 J-row base
        const float b0 = sbias[c0 + 0];
        const float b1 = sbias[c0 + 1];
        const float b2 = sbias[c0 + 2];
        const float b3 = sbias[c0 + 3];
        float* og = outb + c0 * NPAIR;   // 16B-aligned: (c0*741*4) % 16 == 0 for c0%4==0
#pragma unroll
        for (int t = 0; t < 3; ++t) {
            const int k = tid + t * 256;
            if (t == 2 && k >= NPAIR) continue;   // chunks 512..740 -> tid < 229
            float v[4];
#pragma unroll
            for (int m = 0; m < 4; ++m) {
                const float aI = *(const float*)(rI + offIb[t][m]);
                const float aJ = *(const float*)(rJ + offJb[t][m]);
                const int   dc = (int)((dcs[t] >> (2 * m)) & 3u);
                const float bb = dc == 0 ? b0 : dc == 1 ? b1 : dc == 2 ? b2 : b3;
                const float s  = (aI + aJ) + bb;   // same add order as v1/v2 (exactness)
                v[m] = s > 0.0f ? s : 0.0f;
            }
            float4 vv;
            vv.x = v[0]; vv.y = v[1]; vv.z = v[2]; vv.w = v[3];
            ((float4*)og)[k] = vv;   // global_store_dwordx4, 16B-aligned
        }
    }
}

extern "C" void kernel_launch(void* const* d_in, const int* in_sizes, int n_in,
                              void* d_out, int out_size, void* d_ws, size_t ws_size,
                              hipStream_t stream) {
    const float* x    = (const float*)d_in[0];
    const float* W    = (const float*)d_in[1];
    const float* bias = (const float*)d_in[2];
    float* out        = (float*)d_out;

    interconv_fused<<<dim3(BATCH), dim3(256), 0, stream>>>(x, W, bias, out);
}